// Round 10
// baseline (741.260 us; speedup 1.0000x reference)
//
#include <hip/hip_runtime.h>
#include <hip/hip_bf16.h>
#include <hip/hip_fp16.h>
#include <math.h>
#include <float.h>

#define BB 16
#define TT 1023
#define CC 2048
#define M_ROWS (BB * TT)   // 16368
#define MP 16384           // padded rows
#define N3 (3 * CC)        // 6144
#define NCH 16             // scan chunks
#define CHL 64             // chunk length

typedef __attribute__((ext_vector_type(8))) short bfrag;     // 8 bf16 (4 VGPRs)
typedef __attribute__((ext_vector_type(16))) float f32x16;   // 32x32 MFMA C/D
typedef __attribute__((ext_vector_type(4))) short short4v;

__device__ __forceinline__ void async16(const void* g, void* l) {
  __builtin_amdgcn_global_load_lds((const __attribute__((address_space(1))) void*)g,
                                   (__attribute__((address_space(3))) void*)l, 16, 0, 0);
}

__device__ __forceinline__ short bfb(float f) {
  __hip_bfloat16 h = __float2bfloat16(f);
  return *reinterpret_cast<short*>(&h);
}

// ---------------- weight fp32 -> bf16 (float4 vectorized) ----------------
__global__ void cast_weights(const float* __restrict__ Wk, const float* __restrict__ Wv,
                             const float* __restrict__ Wr, const float* __restrict__ Wo,
                             __hip_bfloat16* __restrict__ W3, __hip_bfloat16* __restrict__ WoB) {
  size_t i4 = (size_t)blockIdx.x * 256 + threadIdx.x;      // grid covers CC*CC/4
  size_t i = i4 * 4;
  float4 a = *(const float4*)(Wk + i);
  float4 b = *(const float4*)(Wv + i);
  float4 c = *(const float4*)(Wr + i);
  float4 d = *(const float4*)(Wo + i);
  *(short4v*)((short*)W3 + i)              = short4v{bfb(a.x), bfb(a.y), bfb(a.z), bfb(a.w)};
  *(short4v*)((short*)W3 + i + CC * CC)    = short4v{bfb(b.x), bfb(b.y), bfb(b.z), bfb(b.w)};
  *(short4v*)((short*)W3 + i + 2 * CC * CC) = short4v{bfb(c.x), bfb(c.y), bfb(c.z), bfb(c.w)};
  *(short4v*)((short*)WoB + i)             = short4v{bfb(d.x), bfb(d.y), bfb(d.z), bfb(d.w)};
}

// ---------------- xm = x*tm + shift(x)*(1-tm), bf16, padded to MP rows ----------------
__global__ void build_xm(const float* __restrict__ x, const float* __restrict__ xx,
                         const float* __restrict__ tmix, __hip_bfloat16* __restrict__ xm) {
  int m = blockIdx.x;
  short* orow = (short*)xm + (size_t)m * CC;
  if (m >= M_ROWS) {
    for (int c = threadIdx.x; c < CC / 4; c += 256)
      ((short4v*)orow)[c] = short4v{0, 0, 0, 0};
    return;
  }
  int b = m / TT, t = m - b * TT;
  const float* xrow = x + (size_t)m * CC;
  const float* xprev = (t == 0) ? (xx + (size_t)b * CC) : (xrow - CC);
  for (int c = threadIdx.x; c < CC / 4; c += 256) {
    float4 xv = ((const float4*)xrow)[c];
    float4 pv = ((const float4*)xprev)[c];
    float4 tm = ((const float4*)tmix)[c];
    ((short4v*)orow)[c] = short4v{
        bfb(xv.x * tm.x + pv.x * (1.0f - tm.x)),
        bfb(xv.y * tm.y + pv.y * (1.0f - tm.y)),
        bfb(xv.z * tm.z + pv.z * (1.0f - tm.z)),
        bfb(xv.w * tm.w + pv.w * (1.0f - tm.w))};
  }
}

// ---------------- 256x256-tile 8-phase bf16 MFMA GEMM, 32x32x16 frags ----------------
// C[m,n] = sum_k A[m,k]*B[n,k].  8 waves (2M x 4N), BK=64 as 2 K-halves.
// LDS: 2 buf x 2 khalf x {A,B} regions of 256x32 bf16 (16 KB each) = 128 KB.
// Swizzle: 16B chunk at (row, slot) holds kgrp = slot ^ ((row>>1)&3).
// Schedule = r7's proven 8-phase lockstep (reads before barrier, MFMA after,
// VM(2) at ph4/ph8 -- airtight ledger, measured-best).  ONLY change: MFMA
// shape 16x16x32 -> 32x32x16 (2382 vs 2075 TF ubench; 4x fewer issues; same
// LDS bytes).  A/B frag: row(col)=lane&31, k=(lane>>5)*8+j; two lane offsets
// ldK0/ldK1 because the kstep slot enters the swizzle XOR (non-additive).
template <int MODE>
__global__ __launch_bounds__(512, 2)
void gemm256(const short* __restrict__ A, const short* __restrict__ Bw,
             float* __restrict__ outF, __half* __restrict__ outH,
             __hip_bfloat16* __restrict__ outV, __hip_bfloat16* __restrict__ outR) {
  __shared__ short lds[65536];   // 128 KiB

  const int lane = threadIdx.x & 63, wid = threadIdx.x >> 6;
  const int wr = wid >> 2, wc = wid & 3;

  // XCD-aware swizzle (grids are multiples of 8)
  const int nx = gridDim.x;
  const int nwg = nx * gridDim.y;
  const int bid = blockIdx.y * nx + blockIdx.x;
  const int q = nwg >> 3;
  const int swz = (bid & 7) * q + (bid >> 3);
  const int mBase = (swz / nx) * 256;
  const int nBase = (swz % nx) * 256;

  // staging: wave wid covers rows [wid*32, wid*32+32) of the 256-row region
  const int srow = lane >> 2;                                  // 0..15
  const int scol = (((lane & 3) ^ ((lane >> 3) & 3)) * 8);     // inverse-swizzled k-group
  const int stgOff = wid * 1024 + lane * 8;                    // shorts
  const short* aSrcBase = A  + (size_t)(mBase + wid * 32 + srow) * CC + scol;
  const short* bSrcBase = Bw + (size_t)(nBase + wid * 32 + srow) * CC + scol;

  // 32x32 frag ds_read: row = lane&31, k-half h = lane>>5; kstep ks selects
  // kgrp = ks*2 + h, stored at slot (kgrp ^ ((row>>1)&3)).
  const int r32 = lane & 31;
  const int h5  = lane >> 5;
  const int x3  = (r32 >> 1) & 3;
  const int ldK0 = r32 * 32 + ((h5 ^ x3) * 8);          // ks=0  (shorts)
  const int ldK1 = r32 * 32 + (((2 + h5) ^ x3) * 8);    // ks=1

  // hoisted per-buffer base pointers (kh/mblk/nblk fold into imm offsets)
  const short* a0k0 = lds + wr * 128 * 32 + ldK0;            // buf0 A
  const short* a0k1 = lds + wr * 128 * 32 + ldK1;
  const short* b0k0 = lds + 16384 + wc * 64 * 32 + ldK0;     // buf0 B
  const short* b0k1 = lds + 16384 + wc * 64 * 32 + ldK1;
  const short* a1k0 = a0k0 + 32768;                          // buf1
  const short* a1k1 = a0k1 + 32768;
  const short* b1k0 = b0k0 + 32768;
  const short* b1k1 = b0k1 + 32768;

  f32x16 acc[4][2] = {};   // 4 mblocks x 2 nblocks of 32x32
  bfrag bq[2][2];          // [nblk][kstep], persists across the mh pair

#define RGNA(buf, kh) ((buf) * 32768 + (kh) * 8192)
#define RGNB(buf, kh) (16384 + (buf) * 32768 + (kh) * 8192)

#define STG_A(buf, kh, tk) do { \
    const short* _s = aSrcBase + ((tk) * 64 + (kh) * 32); \
    short* _d = lds + RGNA(buf, kh) + stgOff; \
    async16(_s, _d); async16(_s + (size_t)16 * CC, _d + 512); } while (0)

#define STG_B(buf, kh, tk) do { \
    const short* _s = bSrcBase + ((tk) * 64 + (kh) * 32); \
    short* _d = lds + RGNB(buf, kh) + stgOff; \
    async16(_s, _d); async16(_s + (size_t)16 * CC, _d + 512); } while (0)

#define VMN(n) asm volatile("s_waitcnt vmcnt(" #n ")" ::: "memory")

// phase: {ds_read this phase's frags; stage; barrier; 8x MFMA32; wait; barrier}
#define PH(aK0, aK1, bK0, bK1, kh, mh, STAGE, WAIT) do { \
    bfrag aq[2][2]; \
    if ((mh) == 0) { \
      _Pragma("unroll") \
      for (int nb = 0; nb < 2; ++nb) { \
        bq[nb][0] = *(const bfrag*)(bK0 + (kh) * 8192 + nb * 1024); \
        bq[nb][1] = *(const bfrag*)(bK1 + (kh) * 8192 + nb * 1024); \
      } \
    } \
    _Pragma("unroll") \
    for (int mb = 0; mb < 2; ++mb) { \
      aq[mb][0] = *(const bfrag*)(aK0 + (kh) * 8192 + ((mh) * 64 + mb * 32) * 32); \
      aq[mb][1] = *(const bfrag*)(aK1 + (kh) * 8192 + ((mh) * 64 + mb * 32) * 32); \
    } \
    STAGE; \
    __builtin_amdgcn_s_barrier(); \
    __builtin_amdgcn_s_setprio(1); \
    _Pragma("unroll") \
    for (int mb = 0; mb < 2; ++mb) \
      _Pragma("unroll") \
      for (int nb = 0; nb < 2; ++nb) \
        _Pragma("unroll") \
        for (int ks = 0; ks < 2; ++ks) \
          acc[(mh) * 2 + mb][nb] = __builtin_amdgcn_mfma_f32_32x32x16_bf16( \
              aq[mb][ks], bq[nb][ks], acc[(mh) * 2 + mb][nb], 0, 0, 0); \
    __builtin_amdgcn_s_setprio(0); \
    WAIT; \
    __builtin_amdgcn_s_barrier(); } while (0)

  // prologue: tile0 -> buf0 (4 units), tile1.K0 -> buf1 (2 units);
  // VM(2) retires units 1..5 -> covers iter-0 ph1..4 reads after barrier.
  STG_A(0, 0, 0); STG_B(0, 0, 0);
  STG_A(0, 1, 0); STG_B(0, 1, 0);
  STG_A(1, 0, 1); STG_B(1, 0, 1);
  VMN(2);
  __builtin_amdgcn_s_barrier();

  // steady state (r7 ledger): s1..s8 = A11,B11,A00,B00,A01,B01,A10,B10.
  // ph4-VM(2) lands {prev s7,s8, s1,s2} -> covers ph5..8; ph8-VM(2) lands
  // {s3..s6} -> covers next iter ph1..4.
  for (int ti = 0; ti < 30; ti += 2) {
    PH(a0k0, a0k1, b0k0, b0k1, 0, 0, STG_A(1, 1, ti + 1), );
    PH(a0k0, a0k1, b0k0, b0k1, 0, 1, STG_B(1, 1, ti + 1), );
    PH(a0k0, a0k1, b0k0, b0k1, 1, 0, STG_A(0, 0, ti + 2), );
    PH(a0k0, a0k1, b0k0, b0k1, 1, 1, STG_B(0, 0, ti + 2), VMN(2));
    PH(a1k0, a1k1, b1k0, b1k1, 0, 0, STG_A(0, 1, ti + 2), );
    PH(a1k0, a1k1, b1k0, b1k1, 0, 1, STG_B(0, 1, ti + 2), );
    PH(a1k0, a1k1, b1k0, b1k1, 1, 0, STG_A(1, 0, ti + 3), );
    PH(a1k0, a1k1, b1k0, b1k1, 1, 1, STG_B(1, 0, ti + 3), VMN(2));
  }
  // epilogue: tile 30 in buf0 (staged), tile 31 in buf1 (K0 staged; K1 here).
  PH(a0k0, a0k1, b0k0, b0k1, 0, 0, STG_A(1, 1, 31), );
  PH(a0k0, a0k1, b0k0, b0k1, 0, 1, STG_B(1, 1, 31), );
  PH(a0k0, a0k1, b0k0, b0k1, 1, 0, , );
  PH(a0k0, a0k1, b0k0, b0k1, 1, 1, , VMN(2));   // lands buf1.K0
  PH(a1k0, a1k1, b1k0, b1k1, 0, 0, , );
  PH(a1k0, a1k1, b1k0, b1k1, 0, 1, , VMN(0));   // lands buf1.K1
  PH(a1k0, a1k1, b1k0, b1k1, 1, 0, , );
  PH(a1k0, a1k1, b1k0, b1k1, 1, 1, , );

#undef PH
#undef VMN
#undef STG_A
#undef STG_B
#undef RGNA
#undef RGNB

  // C-write, 32x32 layout (m74/m101): col = lane&31,
  // row = (reg&3) + 8*(reg>>2) + 4*(lane>>5).
#pragma unroll
  for (int mb = 0; mb < 4; ++mb)
#pragma unroll
    for (int nb = 0; nb < 2; ++nb) {
      const int rowb = mBase + wr * 128 + mb * 32 + 4 * h5;
      const int col  = nBase + wc * 64 + nb * 32 + r32;
#pragma unroll
      for (int reg = 0; reg < 16; ++reg) {
        const int row = rowb + (reg & 3) + 8 * (reg >> 2);
        if (row < M_ROWS) {
          float val = acc[mb][nb][reg];
          if constexpr (MODE == 0) {
            outF[(size_t)row * CC + col] = val;
          } else {
            if (col < CC)          outH[(size_t)row * CC + col] = __float2half(expf(val));
            else if (col < 2 * CC) outV[(size_t)row * CC + (col - CC)] = __float2bfloat16(val);
            else                   outR[(size_t)row * CC + (col - 2 * CC)] = __float2bfloat16(val);
          }
        }
      }
    }
}

// ---------------- chunked parallel scan + sigmoid(r)*wkv/wk ----------------
// ek = exp(k) precomputed fp16 by GEMM1 epilogue (renorm-free: ratio invariant;
// state init bb*exp(mm), aa*exp(mm)).
__global__ __launch_bounds__(1024)
void scan_fuse2(const __half* __restrict__ ek, const __hip_bfloat16* __restrict__ v,
                const __hip_bfloat16* __restrict__ r, const float* __restrict__ aa,
                const float* __restrict__ bb, const float* __restrict__ mm,
                const float* __restrict__ tdec, const float* __restrict__ tfir,
                __hip_bfloat16* __restrict__ rwkv) {
  __shared__ float sBk[NCH][64], sBkv[NCH][64], sSk[NCH][64], sSkv[NCH][64];

  const int lane = threadIdx.x & 63, wid = threadIdx.x >> 6;
  const int c = blockIdx.x * 64 + lane;
  const int b = blockIdx.y;
  const int i = b * CC + c;

  const float dexp = expf(tdec[c]);
  const float d    = expf(-dexp);
  const float ef   = expf(tfir[c]);

  const int t0 = wid * CHL;
  const int t1 = (t0 + CHL < TT) ? t0 + CHL : TT;
  const size_t base = (size_t)b * TT * CC + c;

  if (wid < NCH - 1) {
    float Bk = 0.0f, Bkv = 0.0f;
    size_t off = base + (size_t)t0 * CC;
#pragma unroll 4
    for (int t = t0; t < t1; ++t, off += CC) {
      float kk = __half2float(ek[off]);
      float kv = kk * __bfloat162float(v[off]);
      Bk = d * Bk + kk;
      Bkv = d * Bkv + kv;
    }
    sBk[wid][lane] = Bk;
    sBkv[wid][lane] = Bkv;
  }
  __syncthreads();

  if (wid == 0) {
    const float d64 = expf(-dexp * (float)CHL);
    const float sc = expf(mm[i]);
    float S = bb[i] * sc, Sv = aa[i] * sc;
#pragma unroll
    for (int j = 0; j < NCH; ++j) {
      sSk[j][lane] = S;
      sSkv[j][lane] = Sv;
      if (j < NCH - 1) {
        S = d64 * S + sBk[j][lane];
        Sv = d64 * Sv + sBkv[j][lane];
      }
    }
  }
  __syncthreads();

  float S = sSk[wid][lane], Sv = sSkv[wid][lane];
  size_t off = base + (size_t)t0 * CC;
#pragma unroll 4
  for (int t = t0; t < t1; ++t, off += CC) {
    float kk = __half2float(ek[off]);
    float vv = __bfloat162float(v[off]);
    float rv = __bfloat162float(r[off]);
    float kv = kk * vv;
    float wk = ef * kk + S;
    float wkv = ef * kv + Sv;
    S = d * S + kk;
    Sv = d * Sv + kv;
    float ratio = wkv / wk;
    if (isnan(ratio)) ratio = 0.0f;
    else if (isinf(ratio)) ratio = ratio > 0.0f ? FLT_MAX : -FLT_MAX;
    float sig = 1.0f / (1.0f + expf(-rv));
    rwkv[off] = __float2bfloat16(sig * ratio);
  }
}

extern "C" void kernel_launch(void* const* d_in, const int* in_sizes, int n_in,
                              void* d_out, int out_size, void* d_ws, size_t ws_size,
                              hipStream_t stream) {
  const float* x    = (const float*)d_in[0];
  const float* tdec = (const float*)d_in[1];
  const float* tfir = (const float*)d_in[2];
  const float* tmix = (const float*)d_in[3];
  const float* Wk   = (const float*)d_in[4];
  const float* Wv   = (const float*)d_in[5];
  const float* Wr   = (const float*)d_in[6];
  const float* Wo   = (const float*)d_in[7];
  const float* xx   = (const float*)d_in[8];
  const float* aa   = (const float*)d_in[9];
  const float* bb   = (const float*)d_in[10];
  const float* mm   = (const float*)d_in[11];

  char* ws = (char*)d_ws;
  size_t o = 0;
  __hip_bfloat16* W3  = (__hip_bfloat16*)(ws + o); o += (size_t)N3 * CC * 2;
  __hip_bfloat16* WoB = (__hip_bfloat16*)(ws + o); o += (size_t)CC * CC * 2;
  __hip_bfloat16* xmB = (__hip_bfloat16*)(ws + o); o += (size_t)MP * CC * 2;
  __hip_bfloat16* vB  = (__hip_bfloat16*)(ws + o); o += (size_t)MP * CC * 2;
  __hip_bfloat16* rB  = (__hip_bfloat16*)(ws + o); o += (size_t)MP * CC * 2;

  __half* ekH = (__half*)d_out;        // exp(k) fp16 lives in d_out until GEMM2
  __hip_bfloat16* rwkvB = xmB;         // rwkv reuses xm buffer (xm dead after GEMM1)

  cast_weights<<<CC * CC / 1024, 256, 0, stream>>>(Wk, Wv, Wr, Wo, W3, WoB);
  build_xm<<<MP, 256, 0, stream>>>(x, xx, tmix, xmB);
  gemm256<1><<<dim3(N3 / 256, MP / 256), 512, 0, stream>>>(
      (const short*)xmB, (const short*)W3, nullptr, ekH, vB, rB);
  scan_fuse2<<<dim3(CC / 64, BB), 1024, 0, stream>>>(ekH, vB, rB, aa, bb, mm,
                                                     tdec, tfir, rwkvB);
  gemm256<0><<<dim3(CC / 256, MP / 256), 512, 0, stream>>>(
      (const short*)rwkvB, (const short*)WoB, (float*)d_out, nullptr, nullptr, nullptr);
}

// Round 11
// 674.040 us; speedup vs baseline: 1.0997x; 1.0997x over previous
//
#include <hip/hip_runtime.h>
#include <hip/hip_bf16.h>
#include <hip/hip_fp16.h>
#include <math.h>
#include <float.h>

#define BB 16
#define TT 1023
#define CC 2048
#define M_ROWS (BB * TT)   // 16368
#define MP 16384           // padded rows
#define N3 (3 * CC)        // 6144
#define NCH 16             // scan chunks
#define CHL 64             // chunk length

typedef __attribute__((ext_vector_type(8))) short bfrag;   // 8 bf16 (4 VGPRs)
typedef __attribute__((ext_vector_type(4))) float f32x4;   // MFMA C/D frag
typedef __attribute__((ext_vector_type(4))) short short4v;

__device__ __forceinline__ void async16(const void* g, void* l) {
  __builtin_amdgcn_global_load_lds((const __attribute__((address_space(1))) void*)g,
                                   (__attribute__((address_space(3))) void*)l, 16, 0, 0);
}

__device__ __forceinline__ short bfb(float f) {
  __hip_bfloat16 h = __float2bfloat16(f);
  return *reinterpret_cast<short*>(&h);
}

// ---------------- weight fp32 -> bf16 (float4 vectorized) ----------------
__global__ void cast_weights(const float* __restrict__ Wk, const float* __restrict__ Wv,
                             const float* __restrict__ Wr, const float* __restrict__ Wo,
                             __hip_bfloat16* __restrict__ W3, __hip_bfloat16* __restrict__ WoB) {
  size_t i4 = (size_t)blockIdx.x * 256 + threadIdx.x;      // grid covers CC*CC/4
  size_t i = i4 * 4;
  float4 a = *(const float4*)(Wk + i);
  float4 b = *(const float4*)(Wv + i);
  float4 c = *(const float4*)(Wr + i);
  float4 d = *(const float4*)(Wo + i);
  *(short4v*)((short*)W3 + i)              = short4v{bfb(a.x), bfb(a.y), bfb(a.z), bfb(a.w)};
  *(short4v*)((short*)W3 + i + CC * CC)    = short4v{bfb(b.x), bfb(b.y), bfb(b.z), bfb(b.w)};
  *(short4v*)((short*)W3 + i + 2 * CC * CC) = short4v{bfb(c.x), bfb(c.y), bfb(c.z), bfb(c.w)};
  *(short4v*)((short*)WoB + i)             = short4v{bfb(d.x), bfb(d.y), bfb(d.z), bfb(d.w)};
}

// ---------------- xm = x*tm + shift(x)*(1-tm), bf16, padded to MP rows ----------------
__global__ void build_xm(const float* __restrict__ x, const float* __restrict__ xx,
                         const float* __restrict__ tmix, __hip_bfloat16* __restrict__ xm) {
  int m = blockIdx.x;
  short* orow = (short*)xm + (size_t)m * CC;
  if (m >= M_ROWS) {
    for (int c = threadIdx.x; c < CC / 4; c += 256)
      ((short4v*)orow)[c] = short4v{0, 0, 0, 0};
    return;
  }
  int b = m / TT, t = m - b * TT;
  const float* xrow = x + (size_t)m * CC;
  const float* xprev = (t == 0) ? (xx + (size_t)b * CC) : (xrow - CC);
  for (int c = threadIdx.x; c < CC / 4; c += 256) {
    float4 xv = ((const float4*)xrow)[c];
    float4 pv = ((const float4*)xprev)[c];
    float4 tm = ((const float4*)tmix)[c];
    ((short4v*)orow)[c] = short4v{
        bfb(xv.x * tm.x + pv.x * (1.0f - tm.x)),
        bfb(xv.y * tm.y + pv.y * (1.0f - tm.y)),
        bfb(xv.z * tm.z + pv.z * (1.0f - tm.z)),
        bfb(xv.w * tm.w + pv.w * (1.0f - tm.w))};
  }
}

// ---------------- 256x256-tile 8-phase bf16 MFMA GEMM, 16x16x32 frags ----------------
// C[m,n] = sum_k A[m,k]*B[n,k].  8 waves (2M x 4N), BK=64 as 2 K-halves.
// LDS: 2 buf x 2 khalf x {A,B} regions of 256x32 bf16 (16 KB each) = 128 KB.
// Swizzle: 16B chunk at (row, slot) holds kgrp = slot ^ ((row>>1)&3)  (0-conflict,
// verified r3-r9; the 32x32 variant conflicted, reverted).
// r11 change vs r4 (measured best, 414us): ONE barrier per phase instead of two.
//   phase p = { ds_read frags(p); stage s_p; MFMA(p); [VM(4) on ph4/ph8]; barrier }
// Rationale: barrier between reads and MFMA forced LDS-pipe and MFMA-pipe into
// strictly alternating lockstep windows (2312 + 2483 cyc/K-tile, serialized =
// measured 5175).  With the mid-phase barrier gone, a wave enters MFMA as soon
// as its OWN lgkmcnt clears -> MFMA overlaps other waves' LDS service.
// Safety (single barrier): stage(p) region X_p is disjoint from all phase-p
// read regions; X_p's previous readers were at q<p, before barrier(q) ✓.
// VM(4) ledger identical to r4 (airtight: ph4-VM(4) retires {prev s7,s8,s1,s2}
// covering ph5..8 reads; ph8-VM(4) retires {s3..s6} covering next ph1..4).
template <int MODE>
__global__ __launch_bounds__(512, 2)
void gemm256(const short* __restrict__ A, const short* __restrict__ Bw,
             float* __restrict__ outF, __half* __restrict__ outH,
             __hip_bfloat16* __restrict__ outV, __hip_bfloat16* __restrict__ outR) {
  __shared__ short lds[65536];   // 128 KiB

  const int lane = threadIdx.x & 63, wid = threadIdx.x >> 6;
  const int wr = wid >> 2, wc = wid & 3;

  // XCD-aware swizzle (grids are multiples of 8)
  const int nx = gridDim.x;
  const int nwg = nx * gridDim.y;
  const int bid = blockIdx.y * nx + blockIdx.x;
  const int q = nwg >> 3;
  const int swz = (bid & 7) * q + (bid >> 3);
  const int mBase = (swz / nx) * 256;
  const int nBase = (swz % nx) * 256;

  // staging: wave wid covers rows [wid*32, wid*32+32) of the 256-row region
  const int srow = lane >> 2;                                  // 0..15
  const int scol = (((lane & 3) ^ ((lane >> 3) & 3)) * 8);     // inverse-swizzled k-group
  const int stgOff = wid * 1024 + lane * 8;                    // shorts
  const short* aSrcBase = A  + (size_t)(mBase + wid * 32 + srow) * CC + scol;
  const short* bSrcBase = Bw + (size_t)(nBase + wid * 32 + srow) * CC + scol;

  // ds_read: frag lane -> (row = R0 + (l&15), kgrp = l>>4), swizzled slot
  const int ldOff = (lane & 15) * 32 + (((lane >> 4) ^ ((lane >> 1) & 3)) * 8);  // shorts

  f32x4 acc[2][4][4] = {};
  bfrag bq[4];

#define RGNA(buf, kh) ((buf) * 32768 + (kh) * 8192)
#define RGNB(buf, kh) (16384 + (buf) * 32768 + (kh) * 8192)

#define STG_A(buf, kh, tk) do { \
    const short* _s = aSrcBase + ((tk) * 64 + (kh) * 32); \
    short* _d = lds + RGNA(buf, kh) + stgOff; \
    async16(_s, _d); async16(_s + (size_t)16 * CC, _d + 512); } while (0)

#define STG_B(buf, kh, tk) do { \
    const short* _s = bSrcBase + ((tk) * 64 + (kh) * 32); \
    short* _d = lds + RGNB(buf, kh) + stgOff; \
    async16(_s, _d); async16(_s + (size_t)16 * CC, _d + 512); } while (0)

#define VMN(n) asm volatile("s_waitcnt vmcnt(" #n ")" ::: "memory")

// phase: reads ; stage ; MFMA ; wait ; ONE barrier
#define PH(buf, kh, mh, STAGE, WAIT) do { \
    bfrag aq[4]; \
    if ((mh) == 0) { \
      _Pragma("unroll") \
      for (int n = 0; n < 4; ++n) \
        bq[n] = *(const bfrag*)(lds + RGNB(buf, kh) + (wc * 64 + n * 16) * 32 + ldOff); \
    } \
    _Pragma("unroll") \
    for (int f = 0; f < 4; ++f) \
      aq[f] = *(const bfrag*)(lds + RGNA(buf, kh) + (wr * 128 + (mh) * 64 + f * 16) * 32 + ldOff); \
    STAGE; \
    __builtin_amdgcn_s_setprio(1); \
    _Pragma("unroll") \
    for (int f = 0; f < 4; ++f) \
      _Pragma("unroll") \
      for (int n = 0; n < 4; ++n) \
        acc[mh][f][n] = __builtin_amdgcn_mfma_f32_16x16x32_bf16(aq[f], bq[n], acc[mh][f][n], 0, 0, 0); \
    __builtin_amdgcn_s_setprio(0); \
    WAIT; \
    __builtin_amdgcn_s_barrier(); } while (0)

  // prologue: tile0 -> buf0 (4 units), tile1.K0 -> buf1 (2 units).
  // VM(4): units 1..4 (all of buf0) landed; u5,u6 may fly.
  STG_A(0, 0, 0); STG_B(0, 0, 0);
  STG_A(0, 1, 0); STG_B(0, 1, 0);
  STG_A(1, 0, 1); STG_B(1, 0, 1);
  VMN(4);
  __builtin_amdgcn_s_barrier();

  // steady state: s1..s8 = A11,B11,A00,B00,A01,B01,A10,B10 (next tiles).
  // ph4-VM(4): retires {prev s7,s8, s1,s2} -> covers ph5..8 reads (buf1).
  // ph8-VM(4): retires {s3..s6} -> covers next iter ph1..4 reads (buf0).
  for (int ti = 0; ti < 30; ti += 2) {
    PH(0, 0, 0, STG_A(1, 1, ti + 1), );
    PH(0, 0, 1, STG_B(1, 1, ti + 1), );
    PH(0, 1, 0, STG_A(0, 0, ti + 2), );
    PH(0, 1, 1, STG_B(0, 0, ti + 2), VMN(4));
    PH(1, 0, 0, STG_A(0, 1, ti + 2), );
    PH(1, 0, 1, STG_B(0, 1, ti + 2), );
    PH(1, 1, 0, STG_A(1, 0, ti + 3), );
    PH(1, 1, 1, STG_B(1, 0, ti + 3), VMN(4));
  }
  // epilogue: tile 30 in buf0 (staged), tile 31 in buf1 (K0 staged; K1 here).
  // e4-VM(4): retires {s7,s8} (buf1.K0) -> e5-6 reads; e6-VM(0): retires
  // epi {s1,s2} (buf1.K1) -> e7-8 reads.
  PH(0, 0, 0, STG_A(1, 1, 31), );
  PH(0, 0, 1, STG_B(1, 1, 31), );
  PH(0, 1, 0, , );
  PH(0, 1, 1, , VMN(4));
  PH(1, 0, 0, , );
  PH(1, 0, 1, , VMN(0));
  PH(1, 1, 0, , );
  PH(1, 1, 1, , );

#undef PH
#undef VMN
#undef STG_A
#undef STG_B
#undef RGNA
#undef RGNB

  // C-write: col = lane&15, row = (lane>>4)*4 + rr (verified layout)
  // MODE 1: k-cols store exp(k) as fp16 (renorm-free scan reads ek directly).
#pragma unroll
  for (int mh = 0; mh < 2; ++mh)
#pragma unroll
    for (int f = 0; f < 4; ++f) {
      const int row0 = mBase + wr * 128 + mh * 64 + f * 16 + (lane >> 4) * 4;
      const int col0 = nBase + wc * 64 + (lane & 15);
#pragma unroll
      for (int n = 0; n < 4; ++n) {
        const int col = col0 + n * 16;
#pragma unroll
        for (int rr = 0; rr < 4; ++rr) {
          const int row = row0 + rr;
          if (row < M_ROWS) {
            float val = acc[mh][f][n][rr];
            if constexpr (MODE == 0) {
              outF[(size_t)row * CC + col] = val;
            } else {
              if (col < CC)          outH[(size_t)row * CC + col] = __float2half(expf(val));
              else if (col < 2 * CC) outV[(size_t)row * CC + (col - CC)] = __float2bfloat16(val);
              else                   outR[(size_t)row * CC + (col - 2 * CC)] = __float2bfloat16(val);
            }
          }
        }
      }
    }
}

// ---------------- chunked parallel scan + sigmoid(r)*wkv/wk ----------------
// ek = exp(k) precomputed fp16 by GEMM1 epilogue (renorm-free: ratio invariant;
// state init bb*exp(mm), aa*exp(mm)).
__global__ __launch_bounds__(1024)
void scan_fuse2(const __half* __restrict__ ek, const __hip_bfloat16* __restrict__ v,
                const __hip_bfloat16* __restrict__ r, const float* __restrict__ aa,
                const float* __restrict__ bb, const float* __restrict__ mm,
                const float* __restrict__ tdec, const float* __restrict__ tfir,
                __hip_bfloat16* __restrict__ rwkv) {
  __shared__ float sBk[NCH][64], sBkv[NCH][64], sSk[NCH][64], sSkv[NCH][64];

  const int lane = threadIdx.x & 63, wid = threadIdx.x >> 6;
  const int c = blockIdx.x * 64 + lane;
  const int b = blockIdx.y;
  const int i = b * CC + c;

  const float dexp = expf(tdec[c]);
  const float d    = expf(-dexp);
  const float ef   = expf(tfir[c]);

  const int t0 = wid * CHL;
  const int t1 = (t0 + CHL < TT) ? t0 + CHL : TT;
  const size_t base = (size_t)b * TT * CC + c;

  if (wid < NCH - 1) {
    float Bk = 0.0f, Bkv = 0.0f;
    size_t off = base + (size_t)t0 * CC;
#pragma unroll 4
    for (int t = t0; t < t1; ++t, off += CC) {
      float kk = __half2float(ek[off]);
      float kv = kk * __bfloat162float(v[off]);
      Bk = d * Bk + kk;
      Bkv = d * Bkv + kv;
    }
    sBk[wid][lane] = Bk;
    sBkv[wid][lane] = Bkv;
  }
  __syncthreads();

  if (wid == 0) {
    const float d64 = expf(-dexp * (float)CHL);
    const float sc = expf(mm[i]);
    float S = bb[i] * sc, Sv = aa[i] * sc;
#pragma unroll
    for (int j = 0; j < NCH; ++j) {
      sSk[j][lane] = S;
      sSkv[j][lane] = Sv;
      if (j < NCH - 1) {
        S = d64 * S + sBk[j][lane];
        Sv = d64 * Sv + sBkv[j][lane];
      }
    }
  }
  __syncthreads();

  float S = sSk[wid][lane], Sv = sSkv[wid][lane];
  size_t off = base + (size_t)t0 * CC;
#pragma unroll 4
  for (int t = t0; t < t1; ++t, off += CC) {
    float kk = __half2float(ek[off]);
    float vv = __bfloat162float(v[off]);
    float rv = __bfloat162float(r[off]);
    float kv = kk * vv;
    float wk = ef * kk + S;
    float wkv = ef * kv + Sv;
    S = d * S + kk;
    Sv = d * Sv + kv;
    float ratio = wkv / wk;
    if (isnan(ratio)) ratio = 0.0f;
    else if (isinf(ratio)) ratio = ratio > 0.0f ? FLT_MAX : -FLT_MAX;
    float sig = 1.0f / (1.0f + expf(-rv));
    rwkv[off] = __float2bfloat16(sig * ratio);
  }
}

extern "C" void kernel_launch(void* const* d_in, const int* in_sizes, int n_in,
                              void* d_out, int out_size, void* d_ws, size_t ws_size,
                              hipStream_t stream) {
  const float* x    = (const float*)d_in[0];
  const float* tdec = (const float*)d_in[1];
  const float* tfir = (const float*)d_in[2];
  const float* tmix = (const float*)d_in[3];
  const float* Wk   = (const float*)d_in[4];
  const float* Wv   = (const float*)d_in[5];
  const float* Wr   = (const float*)d_in[6];
  const float* Wo   = (const float*)d_in[7];
  const float* xx   = (const float*)d_in[8];
  const float* aa   = (const float*)d_in[9];
  const float* bb   = (const float*)d_in[10];
  const float* mm   = (const float*)d_in[11];

  char* ws = (char*)d_ws;
  size_t o = 0;
  __hip_bfloat16* W3  = (__hip_bfloat16*)(ws + o); o += (size_t)N3 * CC * 2;
  __hip_bfloat16* WoB = (__hip_bfloat16*)(ws + o); o += (size_t)CC * CC * 2;
  __hip_bfloat16* xmB = (__hip_bfloat16*)(ws + o); o += (size_t)MP * CC * 2;
  __hip_bfloat16* vB  = (__hip_bfloat16*)(ws + o); o += (size_t)MP * CC * 2;
  __hip_bfloat16* rB  = (__hip_bfloat16*)(ws + o); o += (size_t)MP * CC * 2;

  __half* ekH = (__half*)d_out;        // exp(k) fp16 lives in d_out until GEMM2
  __hip_bfloat16* rwkvB = xmB;         // rwkv reuses xm buffer (xm dead after GEMM1)

  cast_weights<<<CC * CC / 1024, 256, 0, stream>>>(Wk, Wv, Wr, Wo, W3, WoB);
  build_xm<<<MP, 256, 0, stream>>>(x, xx, tmix, xmB);
  gemm256<1><<<dim3(N3 / 256, MP / 256), 512, 0, stream>>>(
      (const short*)xmB, (const short*)W3, nullptr, ekH, vB, rB);
  scan_fuse2<<<dim3(CC / 64, BB), 1024, 0, stream>>>(ekH, vB, rB, aa, bb, mm,
                                                     tdec, tfir, rwkvB);
  gemm256<0><<<dim3(CC / 256, MP / 256), 512, 0, stream>>>(
      (const short*)rwkvB, (const short*)WoB, (float*)d_out, nullptr, nullptr, nullptr);
}